// Round 3
// baseline (113.148 us; speedup 1.0000x reference)
//
#include <hip/hip_runtime.h>
#include <math.h>

// out[b,s,e] = sum_q cos(x[b,s,q] + theta[q]) * W[e,q]
// B=4, S=4096, E=1024, Q=8  -> tokens = 16384
// Memory-bound on the 67 MB output write; floor ~11 us at 6.3 TB/s.
// R3: same as R2 but nontemporal store via native ext_vector_type
//     (HIP float4 is a class type the builtin rejects).

#define E_DIM 1024
#define Q_DIM 8
#define TPB 256
#define TOK_PER_BLOCK 8

typedef float f32x4 __attribute__((ext_vector_type(4)));

__global__ __launch_bounds__(TPB) void quantum_proj_kernel(
    const float* __restrict__ x,      // [tokens, 1024]
    const float* __restrict__ theta,  // [8]
    const float* __restrict__ W,      // [1024, 8]
    float* __restrict__ out,          // [tokens, 1024]
    int tokens)
{
    __shared__ float P[TOK_PER_BLOCK * Q_DIM];   // 256 B

    const int t    = threadIdx.x;
    const int tok0 = blockIdx.x * TOK_PER_BLOCK;

    // ---- Load this thread's 4 W rows (e = 4t .. 4t+3), 32 contiguous floats.
    const int e0 = t * 4;
    f32x4 wa[4], wb[4];
    {
        const f32x4* W4 = (const f32x4*)W;
        #pragma unroll
        for (int i = 0; i < 4; ++i) {
            wa[i] = W4[(size_t)(e0 + i) * 2 + 0];
            wb[i] = W4[(size_t)(e0 + i) * 2 + 1];
        }
    }

    // ---- Phase 1: threads 0..63 compute cos(x[tok][q] + theta[q]) into LDS
    if (t < TOK_PER_BLOCK * Q_DIM) {
        const int tl  = t >> 3;    // local token
        const int q   = t & 7;
        const int tok = tok0 + tl;
        float v = 0.0f;
        if (tok < tokens) {
            v = cosf(x[(size_t)tok * E_DIM + q] + theta[q]);
        }
        P[t] = v;
    }

    __syncthreads();

    // ---- Phase 2: per token, 32 FMAs + one nontemporal f32x4 store
    // (256 lanes x 16 B = 4 KB contiguous per token; 32 KB contiguous/block)
    #pragma unroll
    for (int tl = 0; tl < TOK_PER_BLOCK; ++tl) {
        const int tok = tok0 + tl;
        if (tok >= tokens) break;

        float p[Q_DIM];
        #pragma unroll
        for (int q = 0; q < Q_DIM; ++q) p[q] = P[tl * Q_DIM + q];  // LDS broadcast

        f32x4 acc;
        acc.x = p[0]*wa[0].x; acc.y = p[0]*wa[1].x;
        acc.z = p[0]*wa[2].x; acc.w = p[0]*wa[3].x;

        acc.x = fmaf(p[1], wa[0].y, acc.x); acc.y = fmaf(p[1], wa[1].y, acc.y);
        acc.z = fmaf(p[1], wa[2].y, acc.z); acc.w = fmaf(p[1], wa[3].y, acc.w);
        acc.x = fmaf(p[2], wa[0].z, acc.x); acc.y = fmaf(p[2], wa[1].z, acc.y);
        acc.z = fmaf(p[2], wa[2].z, acc.z); acc.w = fmaf(p[2], wa[3].z, acc.w);
        acc.x = fmaf(p[3], wa[0].w, acc.x); acc.y = fmaf(p[3], wa[1].w, acc.y);
        acc.z = fmaf(p[3], wa[2].w, acc.z); acc.w = fmaf(p[3], wa[3].w, acc.w);
        acc.x = fmaf(p[4], wb[0].x, acc.x); acc.y = fmaf(p[4], wb[1].x, acc.y);
        acc.z = fmaf(p[4], wb[2].x, acc.z); acc.w = fmaf(p[4], wb[3].x, acc.w);
        acc.x = fmaf(p[5], wb[0].y, acc.x); acc.y = fmaf(p[5], wb[1].y, acc.y);
        acc.z = fmaf(p[5], wb[2].y, acc.z); acc.w = fmaf(p[5], wb[3].y, acc.w);
        acc.x = fmaf(p[6], wb[0].z, acc.x); acc.y = fmaf(p[6], wb[1].z, acc.y);
        acc.z = fmaf(p[6], wb[2].z, acc.z); acc.w = fmaf(p[6], wb[3].z, acc.w);
        acc.x = fmaf(p[7], wb[0].w, acc.x); acc.y = fmaf(p[7], wb[1].w, acc.y);
        acc.z = fmaf(p[7], wb[2].w, acc.z); acc.w = fmaf(p[7], wb[3].w, acc.w);

        f32x4* op = (f32x4*)(out + (size_t)tok * E_DIM) + t;
        __builtin_nontemporal_store(acc, op);
    }
}

extern "C" void kernel_launch(void* const* d_in, const int* in_sizes, int n_in,
                              void* d_out, int out_size, void* d_ws, size_t ws_size,
                              hipStream_t stream) {
    const float* x     = (const float*)d_in[0];
    const float* theta = (const float*)d_in[1];
    const float* W     = (const float*)d_in[2];
    float* out = (float*)d_out;

    const int tokens = in_sizes[0] / E_DIM;            // 16384
    const int grid   = (tokens + TOK_PER_BLOCK - 1) / TOK_PER_BLOCK;  // 2048

    quantum_proj_kernel<<<dim3(grid), dim3(TPB), 0, stream>>>(x, theta, W, out, tokens);
}